// Round 10
// baseline (163.460 us; speedup 1.0000x reference)
//
#include <hip/hip_runtime.h>

#define T_TOTAL 4194304
#define BLK 256
#define PER_TH 16
#define CHUNK (BLK * PER_TH)      // 4096 elements per block
#define NB (T_TOTAL / CHUNK)      // 1024 blocks = 4 per CU
#define NWAVE (BLK / 64)          // 4 waves per block
#define LOOK 1024                 // lookahead: 0.99^1024 ~ 3.4e-5 -> err ~0.02 << 0.595

// True vector type: __builtin_nontemporal_load/store require scalar or vector
// types — HIP's float4 is a struct and does NOT compile with them.
typedef float fx4 __attribute__((ext_vector_type(4)));

// Affine transform: T_i maps v_{i+1} -> v_i = a_i*v_{i+1} + d_i.
// a_i = ter*min(1,ratio) <= 0.99 ALWAYS (deterministic), so carry influence decays
// as 0.99^distance. Each block computes its own carry from LOOK=1024 elements past
// its chunk end — ZERO inter-block sync (validated R9, absmax unchanged).
//
// R9 lesson: PER_TH=32 gave each thread a 128B span/array -> 48KB wave working set
// thrashing the 32KB L1 -> FETCH 165MB (1.46x overfetch) at 3.1TB/s. PER_TH=16
// keeps the k-loop working set at 6 arrays x 4KB = 24KB < L1, span 64B/thread.
//
// Loss: harness zeroes out[] before launch; each block atomicAdds its pre-scaled
// partial into out[0] — accumulated value IS the mean (proven R8).

__global__ __launch_bounds__(BLK) void k_one(
    const float* __restrict__ lp, const float* __restrict__ olp,
    const float* __restrict__ val, const float* __restrict__ nval,
    const float* __restrict__ rew, const float* __restrict__ ter,
    float* __restrict__ out)
{
    __shared__ float wA[NWAVE], wD[NWAVE], rsum[NWAVE];
    __shared__ float sv[CHUNK];
    __shared__ float sCarry;

    const int t = threadIdx.x;
    const int lane = t & 63, w = t >> 6;
    const int c = (int)blockIdx.x;

    // ---- lookahead pass: carry ~= D-composite of the next LOOK elements ----
    // Block-uniform branch; barriers inside are safe. Plain (cacheable) loads:
    // these lines are re-read as main data by block c+1 — let them warm L2.
    float carry = 0.0f;
    if (c < NB - 1) {
        const size_t lb4 = (size_t)(c + 1) * (CHUNK / 4) + (size_t)t;  // 1 fx4/thread
        const fx4 L  = ((const fx4*)lp )[lb4];
        const fx4 O  = ((const fx4*)olp)[lb4];
        const fx4 V  = ((const fx4*)val)[lb4];
        const fx4 N  = ((const fx4*)nval)[lb4];
        const fx4 R  = ((const fx4*)rew)[lb4];
        const fx4 Tm = ((const fx4*)ter)[lb4];
        float A = 1.0f, D = 0.0f;
#pragma unroll
        for (int i = 0; i < 4; ++i) {
            const float rho = fminf(1.0f, __expf(L[i] - O[i]));
            const float ai = Tm[i] * rho;
            const float di = rho * (R[i] + Tm[i] * N[i] - V[i]);
            D = fmaf(A, di, D);
            A *= ai;
        }
        float iA = A, iD = D;
#pragma unroll
        for (int s = 1; s < 64; s <<= 1) {
            const float oA = __shfl_down(iA, s);
            const float oD = __shfl_down(iD, s);
            if (lane + s < 64) { iD = fmaf(iA, oD, iD); iA *= oA; }
        }
        if (lane == 0) { wA[w] = iA; wD[w] = iD; }
        __syncthreads();
        if (t == 0) {
            float TA = 1.0f, TD = 0.0f;
#pragma unroll
            for (int j = 0; j < NWAVE; ++j) { TD = fmaf(TA, wD[j], TD); TA *= wA[j]; }
            sCarry = TD;               // applied to v=0 -> only D matters
        }
        __syncthreads();               // also fences wA/wD for reuse below
        carry = sCarry;
    }

    // ---- main: 16 elements/thread, contiguous [16t, 16t+16) within chunk ----
    float a[PER_TH], d[PER_TH];
    const size_t base4 = (size_t)c * (CHUNK / 4) + 4 * (size_t)t;
#pragma unroll
    for (int k = 0; k < 4; ++k) {
        const fx4 L  = __builtin_nontemporal_load((const fx4*)lp  + base4 + k);
        const fx4 O  = __builtin_nontemporal_load((const fx4*)olp + base4 + k);
        const fx4 V  = __builtin_nontemporal_load((const fx4*)val + base4 + k);
        const fx4 N  = __builtin_nontemporal_load((const fx4*)nval + base4 + k);
        const fx4 R  = __builtin_nontemporal_load((const fx4*)rew + base4 + k);
        const fx4 Tm = __builtin_nontemporal_load((const fx4*)ter + base4 + k);
#pragma unroll
        for (int i = 0; i < 4; ++i) {
            const float rho = fminf(1.0f, __expf(L[i] - O[i]));
            a[4 * k + i] = Tm[i] * rho;
            d[4 * k + i] = rho * (R[i] + Tm[i] * N[i] - V[i]);
        }
    }

    // per-thread composite
    float A = 1.0f, D = 0.0f;
#pragma unroll
    for (int i = 0; i < PER_TH; ++i) { D = fmaf(A, d[i], D); A *= a[i]; }

    // wave inclusive suffix compose (lane l holds composite of lanes l..63)
    float iA = A, iD = D;
#pragma unroll
    for (int s = 1; s < 64; s <<= 1) {
        const float oA = __shfl_down(iA, s);
        const float oD = __shfl_down(iD, s);
        if (lane + s < 64) { iD = fmaf(iA, oD, iD); iA *= oA; }
    }
    if (lane == 0) { wA[w] = iA; wD[w] = iD; }
    __syncthreads();                               // barrier A

    // per-thread exclusive composite within block (elements AFTER this thread's range)
    float SA = 1.0f, SD = 0.0f;
#pragma unroll
    for (int j = 0; j < NWAVE; ++j)
        if (j > w) { SD = fmaf(SA, wD[j], SD); SA *= wA[j]; }
    float eA = __shfl_down(iA, 1);
    float eD = __shfl_down(iD, 1);
    if (lane == 63) { eA = 1.0f; eD = 0.0f; }
    const float EA = eA * SA;
    const float ED = fmaf(eA, SD, eD);

    // ---- apply carry; serial backward recurrence; stage + loss ----
    float v = fmaf(EA, carry, ED);
    float ss = 0.0f;
#pragma unroll
    for (int i = PER_TH - 1; i >= 0; --i) {
        v = fmaf(a[i], v, d[i]);
        d[i] = v;
        ss = fmaf(v, v, ss);
    }

    // stage in LDS, fx4 slot swizzled by k ^ (t&3): unswizzled, the 64B thread
    // stride maps all lanes of a ds_write_b128 onto 8 banks (4x over the b128
    // floor); swizzled, the 4 slot positions spread across all 32 banks.
#pragma unroll
    for (int k = 0; k < 4; ++k) {
        fx4 vv; vv.x = d[4*k+0]; vv.y = d[4*k+1]; vv.z = d[4*k+2]; vv.w = d[4*k+3];
        ((fx4*)sv)[4 * t + (k ^ (t & 3))] = vv;
    }

    // loss: wave butterfly while LDS writes land
#pragma unroll
    for (int s = 32; s > 0; s >>= 1) ss += __shfl_xor(ss, s);
    if (lane == 0) rsum[w] = ss;
    __syncthreads();                               // barrier B

    // coalesced scalar NT stores (out+1 is 4B-misaligned for vector stores);
    // inverse swizzle: element e -> fx4 f=e>>2, writer row r=f>>2, slot s=f&3,
    // physical fx4 p = 4r + (s ^ (r&3)).
    const size_t obase = 1 + (size_t)c * CHUNK;
#pragma unroll
    for (int k = 0; k < PER_TH; ++k) {
        const int e = t + k * BLK;
        const int f = e >> 2, r = f >> 2, s = f & 3;
        const int p = 4 * r + (s ^ (r & 3));
        __builtin_nontemporal_store(sv[4 * p + (e & 3)], &out[obase + e]);
    }

    // loss: one pre-scaled float atomic per block into harness-zeroed out[0]
    if (t == 0) {
        float bs = 0.0f;
#pragma unroll
        for (int j = 0; j < NWAVE; ++j) bs += rsum[j];
        atomicAdd(&out[0], bs * (1.0f / (float)T_TOTAL));
    }
}

extern "C" void kernel_launch(void* const* d_in, const int* in_sizes, int n_in,
                              void* d_out, int out_size, void* d_ws, size_t ws_size,
                              hipStream_t stream) {
    const float* lp   = (const float*)d_in[0];
    const float* olp  = (const float*)d_in[1];
    const float* val  = (const float*)d_in[2];
    const float* nval = (const float*)d_in[3];
    const float* rew  = (const float*)d_in[4];
    const float* ter  = (const float*)d_in[5];
    float* out = (float*)d_out;

    // no workspace use: no sync state, nothing to initialize.
    k_one<<<NB, BLK, 0, stream>>>(lp, olp, val, nval, rew, ter, out);
}

// Round 11
// 144.015 us; speedup vs baseline: 1.1350x; 1.1350x over previous
//
#include <hip/hip_runtime.h>

#define T_TOTAL 4194304
#define BLK 256
#define PER_TH 8
#define CHUNK (BLK * PER_TH)      // 2048 elements per block
#define NB (T_TOTAL / CHUNK)      // 2048 blocks
#define NWAVE (BLK / 64)          // 4 waves per block
#define MAGIC 0xA5C3F00Du         // self-validating publish word: hi = lo ^ MAGIC
#define SPIN_MAX 1024             // bounded spin; then deadlock-proof recompute fallback

// True vector type: __builtin_nontemporal_load/store require scalar or vector
// types — HIP's float4 is a struct and does NOT compile with them.
typedef float fx4 __attribute__((ext_vector_type(4)));

// Affine transform: T_i maps v_{i+1} -> v_i = a_i*v_{i+1} + d_i.
// Chunk composite: v[cC] = A_c * v[(c+1)C] + D_c.
// |A_chunk| <= 0.99^2048 ~ 1.2e-9 deterministically (a_i <= gamma) -> depth-1
// neighbor dependence: carry(c) = D_{c+1}. Producer = blockIdx-1 (launched earlier).
//
// LEDGER (kernel-only time; fixed harness cost ~107us = 2x256MiB ws-poison fills):
//   R8  spin-sync, NT loads:      40.6us, FETCH 53MB (< 100.7MB inputs -> L3-warm!)
//   R9  lookahead, PER_TH=32:     ~58us,  FETCH 165MB (residency destroyed)
//   R10 lookahead, PER_TH=16:     ~58us,  FETCH 153MB
// The fills are streaming writes and do NOT fully evict input lines from the
// 256MiB L3. NT input loads mark lines early-evict and FIGHT that residency.
// This round = R8 exactly, with ONE change: cacheable input loads (NT kept only
// on output stores, which are never re-read).
//
// Loss: harness zeroes out[] before launch; each block atomicAdds its pre-scaled
// partial into out[0] — accumulated value IS the mean (proven R8).

__global__ __launch_bounds__(BLK) void k_single(
    const float* __restrict__ lp, const float* __restrict__ olp,
    const float* __restrict__ val, const float* __restrict__ nval,
    const float* __restrict__ rew, const float* __restrict__ ter,
    unsigned long long* __restrict__ fw,   // NB packed {D|check} words (poison-validated)
    float* __restrict__ out)
{
    __shared__ float wA[NWAVE], wD[NWAVE], rsum[NWAVE];
    __shared__ float sv[CHUNK];
    __shared__ float sCarry;
    __shared__ int sFb;

    const int t = threadIdx.x;
    const int lane = t & 63, w = t >> 6;
    // reversed mapping: chunk c's successor (c+1) belongs to blockIdx-1 (dispatched earlier)
    const int c = NB - 1 - (int)blockIdx.x;
    const size_t base4 = (size_t)c * (CHUNK / 4) + 2 * (size_t)t;  // 2 fx4s/thread

    // ---- phase 1: cacheable read (L3-resident across bench iterations) ----
    float a[PER_TH], d[PER_TH];
#pragma unroll
    for (int k = 0; k < 2; ++k) {
        const fx4 L  = ((const fx4*)lp )[base4 + k];
        const fx4 O  = ((const fx4*)olp)[base4 + k];
        const fx4 V  = ((const fx4*)val)[base4 + k];
        const fx4 N  = ((const fx4*)nval)[base4 + k];
        const fx4 R  = ((const fx4*)rew)[base4 + k];
        const fx4 Tm = ((const fx4*)ter)[base4 + k];
#pragma unroll
        for (int i = 0; i < 4; ++i) {
            const float rho = fminf(1.0f, __expf(L[i] - O[i]));
            a[4 * k + i] = Tm[i] * rho;
            d[4 * k + i] = rho * (R[i] + Tm[i] * N[i] - V[i]);
        }
    }

    float A = 1.0f, D = 0.0f;
#pragma unroll
    for (int i = 0; i < PER_TH; ++i) { D = fmaf(A, d[i], D); A *= a[i]; }

    // wave inclusive suffix compose (lane l holds composite of lanes l..63)
    float iA = A, iD = D;
#pragma unroll
    for (int s = 1; s < 64; s <<= 1) {
        const float oA = __shfl_down(iA, s);
        const float oD = __shfl_down(iD, s);
        if (lane + s < 64) { iD = fmaf(iA, oD, iD); iA *= oA; }
    }
    if (lane == 0) { wA[w] = iA; wD[w] = iD; }
    __syncthreads();                               // barrier 1

    // thread 0: publish this chunk's aggregate D ASAP (single self-validating word;
    // device-scope atomic => cross-XCD coherent; no separate flag/fence needed)
    if (t == 0) {
        float BA = 1.0f, BD = 0.0f;
#pragma unroll
        for (int j = 0; j < NWAVE; ++j) { BD = fmaf(BA, wD[j], BD); BA *= wA[j]; }
        const unsigned lo = __float_as_uint(BD);
        const unsigned long long wv =
            ((unsigned long long)(lo ^ MAGIC) << 32) | (unsigned long long)lo;
        atomicExch(&fw[c], wv);
    }

    // per-thread exclusive composite within block (elements AFTER this thread's range)
    float SA = 1.0f, SD = 0.0f;
#pragma unroll
    for (int j = 0; j < NWAVE; ++j)
        if (j > w) { SD = fmaf(SA, wD[j], SD); SA *= wA[j]; }
    float eA = __shfl_down(iA, 1);
    float eD = __shfl_down(iD, 1);
    if (lane == 63) { eA = 1.0f; eD = 0.0f; }
    const float EA = eA * SA;
    const float ED = fmaf(eA, SD, eD);

    // ---- phase 2: acquire carry = D_{c+1} from neighbor block ----
    if (t == 0) {
        float carry = 0.0f;
        int fb = 0;
        if (c < NB - 1) {
            int got = 0;
#pragma nounroll
            for (int spins = 0; spins < SPIN_MAX; ++spins) {
                const unsigned long long wv = atomicAdd(&fw[c + 1], 0ull); // atomic read
                const unsigned lo = (unsigned)wv, hi = (unsigned)(wv >> 32);
                if ((hi ^ MAGIC) == lo) { carry = __uint_as_float(lo); got = 1; break; }
                __builtin_amdgcn_s_sleep(2);
            }
            if (!got) fb = 1;
        }
        sCarry = carry; sFb = fb;
    }
    __syncthreads();                               // barrier 2 (wA/wD reusable after)

    if (sFb) {
        // deadlock-proof fallback (runs ~never): recompute chunk c+1's D locally.
        // Correctness thus never depends on dispatch order / co-residency (G16).
        const size_t f4 = (size_t)(c + 1) * (CHUNK / 4) + 2 * (size_t)t;
        float fA = 1.0f, fD = 0.0f;
#pragma unroll
        for (int k = 0; k < 2; ++k) {
            const fx4 L  = ((const fx4*)lp )[f4 + k];
            const fx4 O  = ((const fx4*)olp)[f4 + k];
            const fx4 V  = ((const fx4*)val)[f4 + k];
            const fx4 N  = ((const fx4*)nval)[f4 + k];
            const fx4 R  = ((const fx4*)rew)[f4 + k];
            const fx4 Tm = ((const fx4*)ter)[f4 + k];
#pragma unroll
            for (int i = 0; i < 4; ++i) {
                const float rho = fminf(1.0f, __expf(L[i] - O[i]));
                const float ai = Tm[i] * rho;
                const float di = rho * (R[i] + Tm[i] * N[i] - V[i]);
                fD = fmaf(fA, di, fD);
                fA *= ai;
            }
        }
#pragma unroll
        for (int s = 1; s < 64; s <<= 1) {
            const float oA = __shfl_down(fA, s);
            const float oD = __shfl_down(fD, s);
            if (lane + s < 64) { fD = fmaf(fA, oD, fD); fA *= oA; }
        }
        if (lane == 0) { wA[w] = fA; wD[w] = fD; }
        __syncthreads();
        if (t == 0) {
            float BA = 1.0f, BD = 0.0f;
#pragma unroll
            for (int j = 0; j < NWAVE; ++j) { BD = fmaf(BA, wD[j], BD); BA *= wA[j]; }
            sCarry = BD;
        }
        __syncthreads();
    }
    const float carry = sCarry;

    // ---- phase 3: apply carry; serial recurrence; outputs + loss ----
    float v = fmaf(EA, carry, ED);
    float ss = 0.0f;
#pragma unroll
    for (int i = PER_TH - 1; i >= 0; --i) {
        v = fmaf(a[i], v, d[i]);
        d[i] = v;
        ss = fmaf(v, v, ss);
    }

    // stage in LDS for coalesced (out+1 is 4B-misaligned) scalar NT stores
#pragma unroll
    for (int k = 0; k < 2; ++k) {
        fx4 vv; vv.x = d[4*k+0]; vv.y = d[4*k+1]; vv.z = d[4*k+2]; vv.w = d[4*k+3];
        ((fx4*)sv)[2 * t + k] = vv;
    }

    // loss: wave butterfly while LDS writes land
#pragma unroll
    for (int s = 32; s > 0; s >>= 1) ss += __shfl_xor(ss, s);
    if (lane == 0) rsum[w] = ss;
    __syncthreads();                               // barrier 3

    // NT stores: out is never re-read by us — don't evict L3 input lines
    const size_t obase = 1 + (size_t)c * CHUNK;
#pragma unroll
    for (int k = 0; k < PER_TH; ++k)
        __builtin_nontemporal_store(sv[t + k * BLK], &out[obase + t + k * BLK]);

    // loss: one pre-scaled float atomic per block into harness-zeroed out[0]
    if (t == 0) {
        float bs = 0.0f;
#pragma unroll
        for (int j = 0; j < NWAVE; ++j) bs += rsum[j];
        atomicAdd(&out[0], bs * (1.0f / (float)T_TOTAL));
    }
}

extern "C" void kernel_launch(void* const* d_in, const int* in_sizes, int n_in,
                              void* d_out, int out_size, void* d_ws, size_t ws_size,
                              hipStream_t stream) {
    const float* lp   = (const float*)d_in[0];
    const float* olp  = (const float*)d_in[1];
    const float* val  = (const float*)d_in[2];
    const float* nval = (const float*)d_in[3];
    const float* rew  = (const float*)d_in[4];
    const float* ter  = (const float*)d_in[5];
    float* out = (float*)d_out;

    // fw needs NO initialization: publish words are self-validating (hi = lo ^ MAGIC) —
    // uniform poison never matches, and a stale valid word from a prior run of the
    // same graph would hold the identical value (inputs are fixed per capture).
    unsigned long long* fw = (unsigned long long*)((char*)d_ws + 4096);  // NB*8 = 16 KB

    k_single<<<NB, BLK, 0, stream>>>(lp, olp, val, nval, rew, ter, fw, out);
}

// Round 12
// 136.977 us; speedup vs baseline: 1.1933x; 1.0514x over previous
//
#include <hip/hip_runtime.h>

#define T_TOTAL 4194304
#define BLK 1024
#define PER_TH 8
#define CHUNK (BLK * PER_TH)      // 8192 elements per block
#define NB (T_TOTAL / CHUNK)      // 512 blocks = 2 per CU, ALL co-resident at launch
#define NWAVE (BLK / 64)          // 16 waves per block
#define MAGIC 0xA5C3F00Du         // self-validating publish word: hi = lo ^ MAGIC
#define SPIN_MAX 4096             // bounded spin; then deadlock-proof recompute fallback

// True vector type: __builtin_nontemporal_load/store require scalar or vector
// types — HIP's float4 is a struct and does NOT compile with them.
typedef float fx4 __attribute__((ext_vector_type(4)));

// Affine transform: T_i maps v_{i+1} -> v_i = a_i*v_{i+1} + d_i.
// Chunk composite: v[cC] = A_c * v[(c+1)C] + D_c.
// |A_chunk| <= 0.99^8192 (a_i <= gamma always) -> depth-1 neighbor dependence:
// carry(c) = D_{c+1}. Producer of c+1 = blockIdx-1 (dispatched earlier).
//
// LEDGER (kernel time; fixed harness cost ~102-107us = 2x256MiB ws-poison fills):
//   R8  PER_TH=8 spin, NT loads:   40.6us, FETCH 53MB
//   R9  PER_TH=32 lookahead:       ~58us,  FETCH 165MB (128B span thrashes L1)
//   R10 PER_TH=16 lookahead:       ~58us,  FETCH 153MB
//   R11 PER_TH=8 spin, cacheable:  ~42us,  FETCH 49.5MB, 2.8TB/s logical, occ 37%
// NT-vs-cacheable: no effect (L3 keeps ~half the inputs resident either way).
// R11's gap to the 6.4TB/s fill rate is the sync structure: 2048 links, whole
// blocks parked behind one polling thread. This round: SAME proven access
// pattern (32B/thread span), geometry only — BLK=1024, NB=512: 4x fewer links,
// 2 blocks/CU co-resident from t=0 (32 waves/CU).
//
// Loss: harness zeroes out[] before launch; each block atomicAdds its pre-scaled
// partial into out[0] — accumulated value IS the mean (proven R8).

__global__ __launch_bounds__(BLK) void k_single(
    const float* __restrict__ lp, const float* __restrict__ olp,
    const float* __restrict__ val, const float* __restrict__ nval,
    const float* __restrict__ rew, const float* __restrict__ ter,
    unsigned long long* __restrict__ fw,   // NB packed {D|check} words (poison-validated)
    float* __restrict__ out)
{
    __shared__ float wA[NWAVE], wD[NWAVE], rsum[NWAVE];
    __shared__ float sv[CHUNK];
    __shared__ float sCarry;
    __shared__ int sFb;

    const int t = threadIdx.x;
    const int lane = t & 63, w = t >> 6;
    // reversed mapping: chunk c's successor (c+1) belongs to blockIdx-1 (dispatched earlier)
    const int c = NB - 1 - (int)blockIdx.x;
    const size_t base4 = (size_t)c * (CHUNK / 4) + 2 * (size_t)t;  // 2 fx4s/thread, 32B span

    // ---- phase 1: cacheable read (L3-resident across bench iterations) ----
    float a[PER_TH], d[PER_TH];
#pragma unroll
    for (int k = 0; k < 2; ++k) {
        const fx4 L  = ((const fx4*)lp )[base4 + k];
        const fx4 O  = ((const fx4*)olp)[base4 + k];
        const fx4 V  = ((const fx4*)val)[base4 + k];
        const fx4 N  = ((const fx4*)nval)[base4 + k];
        const fx4 R  = ((const fx4*)rew)[base4 + k];
        const fx4 Tm = ((const fx4*)ter)[base4 + k];
#pragma unroll
        for (int i = 0; i < 4; ++i) {
            const float rho = fminf(1.0f, __expf(L[i] - O[i]));
            a[4 * k + i] = Tm[i] * rho;
            d[4 * k + i] = rho * (R[i] + Tm[i] * N[i] - V[i]);
        }
    }

    float A = 1.0f, D = 0.0f;
#pragma unroll
    for (int i = 0; i < PER_TH; ++i) { D = fmaf(A, d[i], D); A *= a[i]; }

    // wave inclusive suffix compose (lane l holds composite of lanes l..63)
    float iA = A, iD = D;
#pragma unroll
    for (int s = 1; s < 64; s <<= 1) {
        const float oA = __shfl_down(iA, s);
        const float oD = __shfl_down(iD, s);
        if (lane + s < 64) { iD = fmaf(iA, oD, iD); iA *= oA; }
    }
    if (lane == 0) { wA[w] = iA; wD[w] = iD; }
    __syncthreads();                               // barrier 1

    // thread 0: publish this chunk's aggregate D ASAP (single self-validating word;
    // device-scope atomic => cross-XCD coherent; no separate flag/fence needed)
    if (t == 0) {
        float BA = 1.0f, BD = 0.0f;
#pragma unroll
        for (int j = 0; j < NWAVE; ++j) { BD = fmaf(BA, wD[j], BD); BA *= wA[j]; }
        const unsigned lo = __float_as_uint(BD);
        const unsigned long long wv =
            ((unsigned long long)(lo ^ MAGIC) << 32) | (unsigned long long)lo;
        atomicExch(&fw[c], wv);
    }

    // per-thread exclusive composite within block (elements AFTER this thread's range)
    float SA = 1.0f, SD = 0.0f;
#pragma unroll
    for (int j = 0; j < NWAVE; ++j)
        if (j > w) { SD = fmaf(SA, wD[j], SD); SA *= wA[j]; }
    float eA = __shfl_down(iA, 1);
    float eD = __shfl_down(iD, 1);
    if (lane == 63) { eA = 1.0f; eD = 0.0f; }
    const float EA = eA * SA;
    const float ED = fmaf(eA, SD, eD);

    // ---- phase 2: acquire carry = D_{c+1} from neighbor block ----
    if (t == 0) {
        float carry = 0.0f;
        int fb = 0;
        if (c < NB - 1) {
            int got = 0;
#pragma nounroll
            for (int spins = 0; spins < SPIN_MAX; ++spins) {
                const unsigned long long wv = atomicAdd(&fw[c + 1], 0ull); // atomic read
                const unsigned lo = (unsigned)wv, hi = (unsigned)(wv >> 32);
                if ((hi ^ MAGIC) == lo) { carry = __uint_as_float(lo); got = 1; break; }
                __builtin_amdgcn_s_sleep(2);
            }
            if (!got) fb = 1;
        }
        sCarry = carry; sFb = fb;
    }
    __syncthreads();                               // barrier 2 (wA/wD reusable after)

    if (sFb) {
        // deadlock-proof fallback (runs ~never): recompute chunk c+1's D locally.
        // Correctness thus never depends on dispatch order / co-residency (G16).
        const size_t f4 = (size_t)(c + 1) * (CHUNK / 4) + 2 * (size_t)t;
        float fA = 1.0f, fD = 0.0f;
#pragma unroll
        for (int k = 0; k < 2; ++k) {
            const fx4 L  = ((const fx4*)lp )[f4 + k];
            const fx4 O  = ((const fx4*)olp)[f4 + k];
            const fx4 V  = ((const fx4*)val)[f4 + k];
            const fx4 N  = ((const fx4*)nval)[f4 + k];
            const fx4 R  = ((const fx4*)rew)[f4 + k];
            const fx4 Tm = ((const fx4*)ter)[f4 + k];
#pragma unroll
            for (int i = 0; i < 4; ++i) {
                const float rho = fminf(1.0f, __expf(L[i] - O[i]));
                const float ai = Tm[i] * rho;
                const float di = rho * (R[i] + Tm[i] * N[i] - V[i]);
                fD = fmaf(fA, di, fD);
                fA *= ai;
            }
        }
#pragma unroll
        for (int s = 1; s < 64; s <<= 1) {
            const float oA = __shfl_down(fA, s);
            const float oD = __shfl_down(fD, s);
            if (lane + s < 64) { fD = fmaf(fA, oD, fD); fA *= oA; }
        }
        if (lane == 0) { wA[w] = fA; wD[w] = fD; }
        __syncthreads();
        if (t == 0) {
            float BA = 1.0f, BD = 0.0f;
#pragma unroll
            for (int j = 0; j < NWAVE; ++j) { BD = fmaf(BA, wD[j], BD); BA *= wA[j]; }
            sCarry = BD;
        }
        __syncthreads();
    }
    const float carry = sCarry;

    // ---- phase 3: apply carry; serial recurrence; outputs + loss ----
    float v = fmaf(EA, carry, ED);
    float ss = 0.0f;
#pragma unroll
    for (int i = PER_TH - 1; i >= 0; --i) {
        v = fmaf(a[i], v, d[i]);
        d[i] = v;
        ss = fmaf(v, v, ss);
    }

    // stage in LDS for coalesced (out+1 is 4B-misaligned) scalar NT stores
#pragma unroll
    for (int k = 0; k < 2; ++k) {
        fx4 vv; vv.x = d[4*k+0]; vv.y = d[4*k+1]; vv.z = d[4*k+2]; vv.w = d[4*k+3];
        ((fx4*)sv)[2 * t + k] = vv;
    }

    // loss: wave butterfly while LDS writes land
#pragma unroll
    for (int s = 32; s > 0; s >>= 1) ss += __shfl_xor(ss, s);
    if (lane == 0) rsum[w] = ss;
    __syncthreads();                               // barrier 3

    // NT stores: out is never re-read by us — don't evict L3 input lines
    const size_t obase = 1 + (size_t)c * CHUNK;
#pragma unroll
    for (int k = 0; k < PER_TH; ++k)
        __builtin_nontemporal_store(sv[t + k * BLK], &out[obase + t + k * BLK]);

    // loss: one pre-scaled float atomic per block into harness-zeroed out[0]
    if (t == 0) {
        float bs = 0.0f;
#pragma unroll
        for (int j = 0; j < NWAVE; ++j) bs += rsum[j];
        atomicAdd(&out[0], bs * (1.0f / (float)T_TOTAL));
    }
}

extern "C" void kernel_launch(void* const* d_in, const int* in_sizes, int n_in,
                              void* d_out, int out_size, void* d_ws, size_t ws_size,
                              hipStream_t stream) {
    const float* lp   = (const float*)d_in[0];
    const float* olp  = (const float*)d_in[1];
    const float* val  = (const float*)d_in[2];
    const float* nval = (const float*)d_in[3];
    const float* rew  = (const float*)d_in[4];
    const float* ter  = (const float*)d_in[5];
    float* out = (float*)d_out;

    // fw needs NO initialization: publish words are self-validating (hi = lo ^ MAGIC) —
    // uniform poison never matches, and a stale valid word from a prior run of the
    // same graph would hold the identical value (inputs are fixed per capture).
    unsigned long long* fw = (unsigned long long*)((char*)d_ws + 4096);  // NB*8 = 4 KB

    k_single<<<NB, BLK, 0, stream>>>(lp, olp, val, nval, rew, ter, fw, out);
}